// Round 4
// baseline (159.291 us; speedup 1.0000x reference)
//
#include <hip/hip_runtime.h>
#include <hip/hip_bf16.h>
#include <stdint.h>

#define N_PTS 4096
#define DIMS  512
#define NBINS 150
#define NREP  8       // histogram replicas (lane & 7)
#define HSTRIDE 9     // NREP + 1 -> bank = (bin*9 + rep) % 32, full spread
#define NTILES 528    // 32*33/2 upper-triangular 128x128 tiles
#define NPANEL 32     // 128-row feature panels / converter blocks
#define MAGIC 0x13579BDFu

typedef short bf16x8 __attribute__((ext_vector_type(8)));
typedef float f32x4  __attribute__((ext_vector_type(4)));

#define AS_G(p) ((const __attribute__((address_space(1))) void*)(p))
#define AS_L(p) ((__attribute__((address_space(3))) void*)(p))

__device__ __forceinline__ unsigned short f2bf(float f) {
  union { float f; unsigned int u; } v; v.f = f;
  unsigned int u = v.u;
  return (unsigned short)((u + 0x7FFFu + ((u >> 16) & 1u)) >> 16);
}

__device__ __forceinline__ float gload_agent(const float* p) {
  return __hip_atomic_load(p, __ATOMIC_RELAXED, __HIP_MEMORY_SCOPE_AGENT);
}

__device__ __forceinline__ void wait_flag(const unsigned int* p) {
  while (__hip_atomic_load(p, __ATOMIC_ACQUIRE, __HIP_MEMORY_SCOPE_AGENT) != MAGIC)
    __builtin_amdgcn_s_sleep(2);
}

// Single fused kernel:
//  phase 0 (blocks 0..31): convert feature panel fp32->bf16 into d_ws, publish
//    release flag; block 0 also zeroes accumulators + done-counter, publishes
//    init flag. Converters never wait before producing -> deadlock-free for
//    any dispatch order / residency.
//  phase 1 (all 528 blocks): acquire panel flags (bi,bj), then 128x128 bf16
//    MFMA tile GEMM + packed-u32 LDS soft histogram.
//  phase 2: acquire init flag, global atomic reduce; last block computes the
//    CDF-overlap loss via wave-scan.
__global__ void __launch_bounds__(256) fused_kernel(
    const float* __restrict__ feats,         // fp32 features [4096][512]
    const int* __restrict__ cls,             // classes [4096]
    unsigned short* __restrict__ fb,         // bf16 features (d_ws)
    float* __restrict__ acc_g,               // [cnt 300][fs 300]
    unsigned int* __restrict__ ctrl,         // [init][done][panel 0..31]
    float* __restrict__ out) {
  const int bid = blockIdx.x;
  // triangular decode (scalar-uniform)
  int t = bid, bi = 0;
  while (t >= 32 - bi) { t -= 32 - bi; ++bi; }
  const int bj = bi + t;

  __shared__ __align__(16) short lds_a[128 * 64];
  __shared__ __align__(16) short lds_b[128 * 64];
  __shared__ unsigned int lds_hist[2 * NBINS * HSTRIDE];  // 10.8 KB
  __shared__ int lds_cls[256];   // [0..127]=rows(bi), [128..255]=cols(bj)
  __shared__ unsigned int last_flag;

  const int tid  = threadIdx.x;
  const int wave = tid >> 6, lane = tid & 63;
  const int wm = wave >> 1, wn = wave & 1;       // 2x2 wave grid, 64x64 each
  const int m16 = lane & 15, quad = lane >> 4;
  const int rep = lane & 7;

  for (int i = tid; i < 2 * NBINS * HSTRIDE; i += 256) lds_hist[i] = 0u;
  {
    int base = (tid < 128 ? bi : bj) * 128;
    lds_cls[tid] = cls[base + (tid & 127)];
  }

  // ---- phase 0: panel conversion (blocks 0..31), block 0 zeroes accs ----
  if (bid < NPANEL) {
    const float4* src = (const float4*)(feats + (size_t)bid * 128 * DIMS);
    ushort4* dst = (ushort4*)(fb + (size_t)bid * 128 * DIMS);
#pragma unroll 1
    for (int c = 0; c < 64; c += 8) {     // 16384 float4 / 256 threads = 64
      float4 v[8];
#pragma unroll
      for (int u = 0; u < 8; ++u) v[u] = src[(c + u) * 256 + tid];
#pragma unroll
      for (int u = 0; u < 8; ++u) {
        ushort4 o;
        o.x = f2bf(v[u].x); o.y = f2bf(v[u].y);
        o.z = f2bf(v[u].z); o.w = f2bf(v[u].w);
        dst[(c + u) * 256 + tid] = o;
      }
    }
    if (bid == 0) {
      for (int i = tid; i < 2 * 2 * NBINS; i += 256) acc_g[i] = 0.0f;
      if (tid == 0) ctrl[1] = 0u;        // done-counter
    }
    __threadfence();
    __syncthreads();                     // all stores drained (vmcnt 0)
    if (tid == 0) {
      __hip_atomic_store(&ctrl[2 + bid], MAGIC,
                         __ATOMIC_RELEASE, __HIP_MEMORY_SCOPE_AGENT);
      if (bid == 0)
        __hip_atomic_store(&ctrl[0], MAGIC,
                           __ATOMIC_RELEASE, __HIP_MEMORY_SCOPE_AGENT);
    }
  }

  // ---- wait for the two panels this tile needs ----
  if (tid == 0) { wait_flag(&ctrl[2 + bi]); wait_flag(&ctrl[2 + bj]); }
  // (K-loop's leading __syncthreads() makes the wait block-wide)

  // Staging: per instr 64 lanes x 16B = 8 rows of 64 bf16. LDS dest slot is
  // lane-forced; XOR-swizzle the SOURCE k-slot so ds_read_b128 is spread.
  const int lrow  = lane >> 3;
  const int lslot = (lane & 7) ^ lrow;
  const size_t rowA0 = (size_t)bi * 128, rowB0 = (size_t)bj * 128;

  f32x4 acc[4][4];
#pragma unroll
  for (int a = 0; a < 4; ++a)
#pragma unroll
    for (int b = 0; b < 4; ++b) acc[a][b] = (f32x4){0.f, 0.f, 0.f, 0.f};

  for (int k0 = 0; k0 < DIMS; k0 += 64) {
    __syncthreads();
#pragma unroll
    for (int c = 0; c < 4; ++c) {
      int inst = wave * 4 + c;
      int row  = inst * 8 + lrow;
      const unsigned short* ga = fb + (rowA0 + row) * DIMS + k0 + lslot * 8;
      const unsigned short* gb = fb + (rowB0 + row) * DIMS + k0 + lslot * 8;
      __builtin_amdgcn_global_load_lds(AS_G(ga), AS_L(&lds_a[inst * 512]), 16, 0, 0);
      __builtin_amdgcn_global_load_lds(AS_G(gb), AS_L(&lds_b[inst * 512]), 16, 0, 0);
    }
    __syncthreads();

#pragma unroll
    for (int ks = 0; ks < 2; ++ks) {
      bf16x8 af[4], bv[4];
      const int q = ks * 4 + quad;
#pragma unroll
      for (int f = 0; f < 4; ++f) {
        int ra = wm * 64 + f * 16 + m16;
        af[f] = *(const bf16x8*)&lds_a[ra * 64 + ((q ^ (ra & 7)) * 8)];
        int rb = wn * 64 + f * 16 + m16;
        bv[f] = *(const bf16x8*)&lds_b[rb * 64 + ((q ^ (rb & 7)) * 8)];
      }
#pragma unroll
      for (int fm = 0; fm < 4; ++fm)
#pragma unroll
        for (int fn = 0; fn < 4; ++fn)
          acc[fm][fn] = __builtin_amdgcn_mfma_f32_16x16x32_bf16(
              af[fm], bv[fn], acc[fm][fn], 0, 0, 0);
    }
  }

  // Epilogue: one packed ds_add_u32 per pair.
  // C/D layout (m89/m91): col = lane&15, row = quad*4 + reg.
  const bool diag = (bi == bj);
  int cj[4], ci[4][4];
#pragma unroll
  for (int fn = 0; fn < 4; ++fn) cj[fn] = lds_cls[128 + wn * 64 + fn * 16 + m16];
#pragma unroll
  for (int fm = 0; fm < 4; ++fm)
#pragma unroll
    for (int r = 0; r < 4; ++r)
      ci[fm][r] = lds_cls[wm * 64 + fm * 16 + quad * 4 + r];

#pragma unroll
  for (int fm = 0; fm < 4; ++fm) {
#pragma unroll
    for (int fn = 0; fn < 4; ++fn) {
#pragma unroll
      for (int r = 0; r < 4; ++r) {
        int i_loc = wm * 64 + fm * 16 + quad * 4 + r;
        int j_loc = wn * 64 + fn * 16 + m16;
        if (diag && j_loc <= i_loc) continue;
        float d = acc[fm][fn][r];
        float x = fmaxf(fmaf(d, 74.5f, 74.5f), 0.0f);  // (d+1)/step, step=2/149
        int idx = (int)x;
        idx = idx > NBINS - 1 ? NBINS - 1 : idx;
        float frac = x - (float)idx;
        unsigned int fx = (unsigned int)fmaf(frac, 4096.0f, 0.5f);
        unsigned int packed = (1u << 22) + fx;
        int sel = (ci[fm][r] == cj[fn]) ? 0 : 1;
        unsigned int off = (unsigned int)(sel * (NBINS * HSTRIDE) + idx * HSTRIDE + rep);
        __hip_atomic_fetch_add(&lds_hist[off], packed,
                               __ATOMIC_RELAXED, __HIP_MEMORY_SCOPE_WORKGROUP);
      }
    }
  }

  __syncthreads();
  // ---- phase 2: global reduce (wait for accumulator init first) ----
  if (tid == 0) wait_flag(&ctrl[0]);
  __syncthreads();
  for (int e = tid; e < 2 * NBINS; e += 256) {
    unsigned int cnt = 0, fs = 0;
    const unsigned int* h = &lds_hist[e * HSTRIDE];
#pragma unroll
    for (int rp = 0; rp < NREP; ++rp) {
      unsigned int v = h[rp];
      cnt += v >> 22;
      fs  += v & 0x3FFFFFu;
    }
    if (cnt) {
      unsafeAtomicAdd(&acc_g[e], (float)cnt);              // cnt[2][150]
      unsafeAtomicAdd(&acc_g[2 * NBINS + e], (float)fs);   // fs[2][150]
    }
  }

  // Last block finalizes: reconstruct hists, CDF via wave scan, overlap loss.
  __syncthreads();   // this block's atomics drained
  if (tid == 0) {
    __threadfence();
    unsigned int prev = atomicAdd(&ctrl[1], 1u);
    last_flag = (prev == NTILES - 1) ? 1u : 0u;
  }
  __syncthreads();
  if (last_flag && tid < 64) {
    __threadfence();
    const float is = 1.0f / 4096.0f;
    const float* cntp = acc_g;               // [2][150]
    const float* fsp  = acc_g + 2 * NBINS;   // [2][150]
    // pass 1: totals
    float sp = 0.f, sn = 0.f;
#pragma unroll
    for (int rr = 0; rr < 3; ++rr) {
      int b = rr * 64 + lane;
      if (b < NBINS) {
        sp += gload_agent(cntp + b);
        sn += gload_agent(cntp + NBINS + b);
      }
    }
#pragma unroll
    for (int o = 32; o; o >>= 1) { sp += __shfl_xor(sp, o); sn += __shfl_xor(sn, o); }
    // pass 2: scan + dot
    float carry = 0.f, pf0 = 0.f, pf1 = 0.f, lacc = 0.f;
#pragma unroll
    for (int rr = 0; rr < 3; ++rr) {
      int b = rr * 64 + lane;
      bool ok = b < NBINS;
      float c0 = ok ? gload_agent(cntp + b) : 0.f;
      float f0 = ok ? gload_agent(fsp + b) : 0.f;
      float c1 = ok ? gload_agent(cntp + NBINS + b) : 0.f;
      float f1 = ok ? gload_agent(fsp + NBINS + b) : 0.f;
      float f0m1 = __shfl_up(f0, 1); if (lane == 0) f0m1 = pf0;
      float f1m1 = __shfl_up(f1, 1); if (lane == 0) f1m1 = pf1;
      float hp = ok ? (c0 + (f0m1 - f0) * is) : 0.f;
      float hn = ok ? (c1 + (f1m1 - f1) * is) : 0.f;
      if (b == NBINS - 1) { hp += f0 * is; hn += f1 * is; }
      float s = hp;
#pragma unroll
      for (int o = 1; o < 64; o <<= 1) {
        float u = __shfl_up(s, o);
        if (lane >= o) s += u;
      }
      if (ok) lacc += hn * ((carry + s) / sp);
      carry += __shfl(s, 63);
      pf0 = __shfl(f0, 63); pf1 = __shfl(f1, 63);
    }
#pragma unroll
    for (int o = 32; o; o >>= 1) lacc += __shfl_xor(lacc, o);
    if (lane == 0) out[0] = lacc / sn;
  }
}

extern "C" void kernel_launch(void* const* d_in, const int* in_sizes, int n_in,
                              void* d_out, int out_size, void* d_ws, size_t ws_size,
                              hipStream_t stream) {
  const float* feats   = (const float*)d_in[0];
  const int*   classes = (const int*)d_in[1];
  unsigned short* fb   = (unsigned short*)d_ws;                      // 4 MB bf16
  float* acc_g = (float*)((char*)d_ws + (size_t)N_PTS * DIMS * 2);   // 600 floats
  unsigned int* ctrl = (unsigned int*)((char*)d_ws + (size_t)N_PTS * DIMS * 2 + 2560);
  float* out   = (float*)d_out;

  hipLaunchKernelGGL(fused_kernel, dim3(NTILES), dim3(256), 0, stream,
                     feats, classes, fb, acc_g, ctrl, out);
}

// Round 5
// 85.918 us; speedup vs baseline: 1.8540x; 1.8540x over previous
//
#include <hip/hip_runtime.h>
#include <hip/hip_bf16.h>
#include <stdint.h>

#define N_PTS 4096
#define DIMS  512
#define NBINS 150
#define NREP  4       // LDS histogram replicas (lane & 3)
#define HSTRIDE 5     // NREP + 1 -> bank stride 5 (gcd(5,32)=1, full spread)
#define GREP  16      // global accumulator replicas (bid & 15)
#define NTILES 528    // 32*33/2 upper-triangular 128x128 tiles

typedef short bf16x8 __attribute__((ext_vector_type(8)));
typedef float f32x4  __attribute__((ext_vector_type(4)));

#define AS_G(p) ((const __attribute__((address_space(1))) void*)(p))
#define AS_L(p) ((__attribute__((address_space(3))) void*)(p))

__device__ __forceinline__ unsigned short f2bf(float f) {
  union { float f; unsigned int u; } v; v.f = f;
  unsigned int u = v.u;
  return (unsigned short)((u + 0x7FFFu + ((u >> 16) & 1u)) >> 16);
}

__device__ __forceinline__ float gload_agent(const float* p) {
  return __hip_atomic_load(p, __ATOMIC_RELAXED, __HIP_MEMORY_SCOPE_AGENT);
}

// Kernel 1 (wide, 2048 blocks): fp32 -> bf16 feature conversion + zero the
// replicated global accumulators (GREP x [cnt 2x150 | fs 2x150]) + counter.
__global__ void convert_kernel(const float* __restrict__ in,
                               unsigned short* __restrict__ out,
                               float* __restrict__ acc_g) {
  int t = blockIdx.x * blockDim.x + threadIdx.x;   // one float4 per thread
  float4 v = ((const float4*)in)[t];
  ushort4 o;
  o.x = f2bf(v.x); o.y = f2bf(v.y); o.z = f2bf(v.z); o.w = f2bf(v.w);
  ((ushort4*)out)[t] = o;
  if (t < GREP * 4 * NBINS + 4) acc_g[t] = 0.0f;   // includes counter word
}

// Kernel 2: fused GEMM (bf16 MFMA) + soft histogram + last-block finalize.
// Triangular grid: block -> tile (bi,bj), bj>=bi; diagonal takes j>i only.
// Soft binning: ONE packed u32 LDS atomic per pair: (1<<22) + round(frac*4096)
// into cell [sel][idx][lane&3]; per-cell cnt <= ~500 < 1023 (10-bit field),
// fs <= ~2.1M < 2^22.  hist[b] = cnt[b] - fs[b]/4096 + fs[b-1]/4096
// (+ fs[149]/4096 at b=149).  Global push goes to replica bid&15 to avoid
// same-address atomic serialization across 528 blocks.
__global__ void __launch_bounds__(256, 4) fused_kernel(
    const unsigned short* __restrict__ fb,   // bf16 features [4096][512]
    const int* __restrict__ cls,             // classes [4096]
    float* __restrict__ acc_g,               // [GREP][600] + ctr
    float* __restrict__ out) {
  // triangular decode (scalar-uniform, <=32 iterations)
  int t = blockIdx.x, bi = 0;
  while (t >= 32 - bi) { t -= 32 - bi; ++bi; }
  const int bj = bi + t;

  __shared__ __align__(16) short lds_a[128 * 64];
  __shared__ __align__(16) short lds_b[128 * 64];
  __shared__ unsigned int lds_hist[2 * NBINS * HSTRIDE];  // 6000 B (reused as fin[600])
  __shared__ int lds_cls[256];   // [0..127]=rows(bi), [128..255]=cols(bj)
  __shared__ unsigned int last_flag;

  const int tid  = threadIdx.x;
  const int wave = tid >> 6, lane = tid & 63;
  const int wm = wave >> 1, wn = wave & 1;       // 2x2 wave grid, 64x64 each
  const int m16 = lane & 15, quad = lane >> 4;
  const int rep = lane & (NREP - 1);

  for (int i = tid; i < 2 * NBINS * HSTRIDE; i += 256) lds_hist[i] = 0u;
  {
    int base = (tid < 128 ? bi : bj) * 128;
    lds_cls[tid] = cls[base + (tid & 127)];
  }

  // Staging: per instr 64 lanes x 16B = 8 rows of 64 bf16. LDS dest slot is
  // lane-forced; XOR-swizzle the SOURCE k-slot so ds_read_b128 is spread.
  const int lrow  = lane >> 3;
  const int lslot = (lane & 7) ^ lrow;
  const size_t rowA0 = (size_t)bi * 128, rowB0 = (size_t)bj * 128;

  f32x4 acc[4][4];
#pragma unroll
  for (int a = 0; a < 4; ++a)
#pragma unroll
    for (int b = 0; b < 4; ++b) acc[a][b] = (f32x4){0.f, 0.f, 0.f, 0.f};

  for (int k0 = 0; k0 < DIMS; k0 += 64) {
    __syncthreads();
#pragma unroll
    for (int c = 0; c < 4; ++c) {
      int inst = wave * 4 + c;
      int row  = inst * 8 + lrow;
      const unsigned short* ga = fb + (rowA0 + row) * DIMS + k0 + lslot * 8;
      const unsigned short* gb = fb + (rowB0 + row) * DIMS + k0 + lslot * 8;
      __builtin_amdgcn_global_load_lds(AS_G(ga), AS_L(&lds_a[inst * 512]), 16, 0, 0);
      __builtin_amdgcn_global_load_lds(AS_G(gb), AS_L(&lds_b[inst * 512]), 16, 0, 0);
    }
    __syncthreads();

#pragma unroll
    for (int ks = 0; ks < 2; ++ks) {
      bf16x8 af[4], bv[4];
      const int q = ks * 4 + quad;
#pragma unroll
      for (int f = 0; f < 4; ++f) {
        int ra = wm * 64 + f * 16 + m16;
        af[f] = *(const bf16x8*)&lds_a[ra * 64 + ((q ^ (ra & 7)) * 8)];
        int rb = wn * 64 + f * 16 + m16;
        bv[f] = *(const bf16x8*)&lds_b[rb * 64 + ((q ^ (rb & 7)) * 8)];
      }
#pragma unroll
      for (int fm = 0; fm < 4; ++fm)
#pragma unroll
        for (int fn = 0; fn < 4; ++fn)
          acc[fm][fn] = __builtin_amdgcn_mfma_f32_16x16x32_bf16(
              af[fm], bv[fn], acc[fm][fn], 0, 0, 0);
    }
  }

  // Epilogue: one packed ds_add_u32 per pair.
  // C/D layout (m89/m91): col = lane&15, row = quad*4 + reg.
  const bool diag = (bi == bj);
  int cj[4], ci[4][4];
#pragma unroll
  for (int fn = 0; fn < 4; ++fn) cj[fn] = lds_cls[128 + wn * 64 + fn * 16 + m16];
#pragma unroll
  for (int fm = 0; fm < 4; ++fm)
#pragma unroll
    for (int r = 0; r < 4; ++r)
      ci[fm][r] = lds_cls[wm * 64 + fm * 16 + quad * 4 + r];

#pragma unroll
  for (int fm = 0; fm < 4; ++fm) {
#pragma unroll
    for (int fn = 0; fn < 4; ++fn) {
#pragma unroll
      for (int r = 0; r < 4; ++r) {
        int i_loc = wm * 64 + fm * 16 + quad * 4 + r;
        int j_loc = wn * 64 + fn * 16 + m16;
        if (diag && j_loc <= i_loc) continue;
        float d = acc[fm][fn][r];
        float x = fmaxf(fmaf(d, 74.5f, 74.5f), 0.0f);  // (d+1)/step, step=2/149
        int idx = (int)x;
        idx = idx > NBINS - 1 ? NBINS - 1 : idx;
        float frac = x - (float)idx;
        unsigned int fx = (unsigned int)fmaf(frac, 4096.0f, 0.5f);
        unsigned int packed = (1u << 22) + fx;
        int sel = (ci[fm][r] == cj[fn]) ? 0 : 1;
        unsigned int off = (unsigned int)(sel * (NBINS * HSTRIDE) + idx * HSTRIDE + rep);
        __hip_atomic_fetch_add(&lds_hist[off], packed,
                               __ATOMIC_RELAXED, __HIP_MEMORY_SCOPE_WORKGROUP);
      }
    }
  }

  __syncthreads();
  // Global push to replica (bid & 15); skip untouched bins.
  float* myacc = acc_g + (blockIdx.x & (GREP - 1)) * (4 * NBINS);
  for (int e = tid; e < 2 * NBINS; e += 256) {
    unsigned int cnt = 0, fs = 0;
    const unsigned int* h = &lds_hist[e * HSTRIDE];
#pragma unroll
    for (int rp = 0; rp < NREP; ++rp) {
      unsigned int v = h[rp];
      cnt += v >> 22;
      fs  += v & 0x3FFFFFu;
    }
    if (cnt) {
      unsafeAtomicAdd(&myacc[e], (float)cnt);              // cnt[2][150]
      unsafeAtomicAdd(&myacc[2 * NBINS + e], (float)fs);   // fs[2][150]
    }
  }

  // Last block finalizes.
  __syncthreads();   // this block's atomics drained
  if (tid == 0) {
    __threadfence();
    unsigned int prev = atomicAdd((unsigned int*)(acc_g + GREP * 4 * NBINS), 1u);
    last_flag = (prev == NTILES - 1) ? 1u : 0u;
  }
  __syncthreads();
  if (last_flag) {
    __threadfence();
    float* fin = (float*)lds_hist;         // reuse: 600 floats
    for (int e = tid; e < 4 * NBINS; e += 256) {
      float s = 0.f;
#pragma unroll
      for (int rp = 0; rp < GREP; ++rp)
        s += gload_agent(acc_g + rp * (4 * NBINS) + e);
      fin[e] = s;
    }
    __syncthreads();
    if (tid < 64) {
      const float is = 1.0f / 4096.0f;
      const float* cntp = fin;             // [2][150]
      const float* fsp  = fin + 2 * NBINS; // [2][150]
      // pass 1: totals
      float sp = 0.f, sn = 0.f;
#pragma unroll
      for (int rr = 0; rr < 3; ++rr) {
        int b = rr * 64 + lane;
        if (b < NBINS) { sp += cntp[b]; sn += cntp[NBINS + b]; }
      }
#pragma unroll
      for (int o = 32; o; o >>= 1) { sp += __shfl_xor(sp, o); sn += __shfl_xor(sn, o); }
      // pass 2: scan + dot
      float carry = 0.f, pf0 = 0.f, pf1 = 0.f, lacc = 0.f;
#pragma unroll
      for (int rr = 0; rr < 3; ++rr) {
        int b = rr * 64 + lane;
        bool ok = b < NBINS;
        float c0 = ok ? cntp[b] : 0.f;
        float f0 = ok ? fsp[b] : 0.f;
        float c1 = ok ? cntp[NBINS + b] : 0.f;
        float f1 = ok ? fsp[NBINS + b] : 0.f;
        float f0m1 = __shfl_up(f0, 1); if (lane == 0) f0m1 = pf0;
        float f1m1 = __shfl_up(f1, 1); if (lane == 0) f1m1 = pf1;
        float hp = ok ? (c0 + (f0m1 - f0) * is) : 0.f;
        float hn = ok ? (c1 + (f1m1 - f1) * is) : 0.f;
        if (b == NBINS - 1) { hp += f0 * is; hn += f1 * is; }
        float s = hp;
#pragma unroll
        for (int o = 1; o < 64; o <<= 1) {
          float u = __shfl_up(s, o);
          if (lane >= o) s += u;
        }
        if (ok) lacc += hn * ((carry + s) / sp);
        carry += __shfl(s, 63);
        pf0 = __shfl(f0, 63); pf1 = __shfl(f1, 63);
      }
#pragma unroll
      for (int o = 32; o; o >>= 1) lacc += __shfl_xor(lacc, o);
      if (lane == 0) out[0] = lacc / sn;
    }
  }
}

extern "C" void kernel_launch(void* const* d_in, const int* in_sizes, int n_in,
                              void* d_out, int out_size, void* d_ws, size_t ws_size,
                              hipStream_t stream) {
  const float* feats   = (const float*)d_in[0];
  const int*   classes = (const int*)d_in[1];
  unsigned short* fb   = (unsigned short*)d_ws;                      // 4 MB bf16
  float* acc_g = (float*)((char*)d_ws + (size_t)N_PTS * DIMS * 2);   // GREP*600 + ctr
  float* out   = (float*)d_out;

  hipLaunchKernelGGL(convert_kernel, dim3((N_PTS * DIMS / 4) / 256), dim3(256), 0, stream,
                     feats, fb, acc_g);
  hipLaunchKernelGGL(fused_kernel, dim3(NTILES), dim3(256), 0, stream,
                     fb, classes, acc_g, out);
}